// Round 9
// baseline (498.030 us; speedup 1.0000x reference)
//
#include <hip/hip_runtime.h>

namespace {

typedef float f2 __attribute__((ext_vector_type(2)));

constexpr int BATCH = 32768;
constexpr int STEPS = 20;
constexpr int WD    = 48;
constexpr int WAVES = 6;           // waves per block
constexpr int IPW   = 8;           // units per wave (WAVES*IPW == WD)
constexpr int NCH   = WD / 4;      // 12 k-chunks of 4
constexpr float LR   = 0.1f;
constexpr float B1C  = 0.9f;
constexpr float B2C  = 0.999f;
constexpr float AEPS = 1e-8f;

__device__ __forceinline__ void swish3(float z, float& a, float& d1, float& d2) {
    const float sg = 1.f / (1.f + __expf(-z));
    const float sp = sg * (1.f - sg);
    d1 = fmaf(z, sp, sg);                      // swish'
    d2 = sp * fmaf(z, 1.f - 2.f * sg, 2.f);    // swish''
    a  = z * sg;
}

// Forced packed FMA: acc(pair) += w(SGPR pair) * a(pair). VOP3P allows one
// scalar source, so s_load'ed weights feed directly with no v_mov.
__device__ __forceinline__ void pkfma_s(f2& acc, f2 w, f2 a) {
    asm("v_pk_fma_f32 %0, %1, %2, %0" : "+v"(acc) : "s"(w), "v"(a));
}

// Sample-per-lane; 6 waves x 8 units. LDS act buffers are chunk-major
// [buf][NCH][64][4] (lane-stride 16B -> conflict-free b128 reads/writes),
// ping-ponged across layers so only 3 barriers/step. Weights uniform ->
// s_load on the scalar pipe; inner loop is v_pk_fma_f32 (forced).
__global__ __launch_bounds__(384, 3) void ebm_kernel(
    const float* __restrict__ x_in,  const float* __restrict__ eps_in,
    const float* __restrict__ W1,    const float* __restrict__ b1,
    const float* __restrict__ W2,    const float* __restrict__ b2,
    const float* __restrict__ W3,    const float* __restrict__ b3,
    const float* __restrict__ W4,
    float* __restrict__ out)
{
    const int lane = threadIdx.x & 63;
    const int wid  = __builtin_amdgcn_readfirstlane(threadIdx.x >> 6);
    const int s    = blockIdx.x * 64 + lane;
    const int u0   = wid * IPW;                 // first unit owned by this wave
    const int c0   = wid * 2;                   // first chunk owned (IPW/4 == 2)

    __shared__ float aV[2][NCH][64][4];         // value channel, ping-pong
    __shared__ float aP[2][NCH][64][4];         // d/dy
    __shared__ float aQ[2][NCH][64][4];         // d2/dy2
    __shared__ float2 pdS[WAVES][64];           // per-wave (E', E'') partials

    const float4* __restrict__ W2v4 = reinterpret_cast<const float4*>(W2);
    const float4* __restrict__ W3v4 = reinterpret_cast<const float4*>(W3);

    const float xv = x_in[s];
    float y = 0.f, m = 0.f, v = 0.f;
    float pb1 = 1.f, pb2 = 1.f;

    for (int t = 0; t < STEPS; ++t) {
        const float e  = eps_in[t * BATCH + s];
        const float y0 = y + e;
        pb1 *= B1C; pb2 *= B2C;

        // ---- layer 1 (2 -> 48): this wave's 8 units -> buf0 ----
        float oa[IPW], op[IPW], oq[IPW];
#pragma unroll
        for (int ii = 0; ii < IPW; ++ii) {
            const int i = u0 + ii;
            const float w1x = W1[2 * i];
            const float w1y = W1[2 * i + 1];
            const float z1 = fmaf(w1y, y0, fmaf(w1x, xv, b1[i]));
            float a, d1, d2; swish3(z1, a, d1, d2);
            oa[ii] = a; op[ii] = d1 * w1y; oq[ii] = d2 * w1y * w1y;
        }
#pragma unroll
        for (int c = 0; c < IPW / 4; ++c) {
            *reinterpret_cast<float4*>(aV[0][c0 + c][lane]) = make_float4(oa[4*c], oa[4*c+1], oa[4*c+2], oa[4*c+3]);
            *reinterpret_cast<float4*>(aP[0][c0 + c][lane]) = make_float4(op[4*c], op[4*c+1], op[4*c+2], op[4*c+3]);
            *reinterpret_cast<float4*>(aQ[0][c0 + c][lane]) = make_float4(oq[4*c], oq[4*c+1], oq[4*c+2], oq[4*c+3]);
        }
        __syncthreads();                         // b1: L1 acts (buf0) visible

        // ---- layer 2 (48 -> 48): read buf0, packed FMA, write buf1 ----
        f2 az[IPW], ap2[IPW], aq2[IPW];
#pragma unroll
        for (int ii = 0; ii < IPW; ++ii) {
            az[ii]  = f2{b2[u0 + ii], 0.f};
            ap2[ii] = f2{0.f, 0.f};
            aq2[ii] = f2{0.f, 0.f};
        }
#pragma unroll 2
        for (int kc = 0; kc < NCH; ++kc) {
            const float4 cv = *reinterpret_cast<const float4*>(aV[0][kc][lane]);
            const float4 cp = *reinterpret_cast<const float4*>(aP[0][kc][lane]);
            const float4 cq = *reinterpret_cast<const float4*>(aQ[0][kc][lane]);
            const f2 cv01 = f2{cv.x, cv.y}, cv23 = f2{cv.z, cv.w};
            const f2 cp01 = f2{cp.x, cp.y}, cp23 = f2{cp.z, cp.w};
            const f2 cq01 = f2{cq.x, cq.y}, cq23 = f2{cq.z, cq.w};
#pragma unroll
            for (int ii = 0; ii < IPW; ++ii) {
                const float4 w = W2v4[(u0 + ii) * NCH + kc];   // uniform -> s_load_dwordx4
                const f2 w01 = f2{w.x, w.y}, w23 = f2{w.z, w.w};
                pkfma_s(az[ii],  w01, cv01);  pkfma_s(az[ii],  w23, cv23);
                pkfma_s(ap2[ii], w01, cp01);  pkfma_s(ap2[ii], w23, cp23);
                pkfma_s(aq2[ii], w01, cq01);  pkfma_s(aq2[ii], w23, cq23);
            }
        }
#pragma unroll
        for (int ii = 0; ii < IPW; ++ii) {
            const float z2 = az[ii].x + az[ii].y;
            const float zp = ap2[ii].x + ap2[ii].y;
            const float zq = aq2[ii].x + aq2[ii].y;
            float a, d1, d2; swish3(z2, a, d1, d2);
            oa[ii] = a;
            op[ii] = d1 * zp;
            oq[ii] = fmaf(d2 * zp, zp, d1 * zq);
        }
#pragma unroll
        for (int c = 0; c < IPW / 4; ++c) {
            *reinterpret_cast<float4*>(aV[1][c0 + c][lane]) = make_float4(oa[4*c], oa[4*c+1], oa[4*c+2], oa[4*c+3]);
            *reinterpret_cast<float4*>(aP[1][c0 + c][lane]) = make_float4(op[4*c], op[4*c+1], op[4*c+2], op[4*c+3]);
            *reinterpret_cast<float4*>(aQ[1][c0 + c][lane]) = make_float4(oq[4*c], oq[4*c+1], oq[4*c+2], oq[4*c+3]);
        }
        __syncthreads();                         // b2: buf1 visible AND all
                                                 // buf0 reads complete

        // ---- layer 3 (48 -> 48) from buf1 + W4 dot ----
#pragma unroll
        for (int ii = 0; ii < IPW; ++ii) {
            az[ii]  = f2{b3[u0 + ii], 0.f};
            ap2[ii] = f2{0.f, 0.f};
            aq2[ii] = f2{0.f, 0.f};
        }
#pragma unroll 2
        for (int kc = 0; kc < NCH; ++kc) {
            const float4 cv = *reinterpret_cast<const float4*>(aV[1][kc][lane]);
            const float4 cp = *reinterpret_cast<const float4*>(aP[1][kc][lane]);
            const float4 cq = *reinterpret_cast<const float4*>(aQ[1][kc][lane]);
            const f2 cv01 = f2{cv.x, cv.y}, cv23 = f2{cv.z, cv.w};
            const f2 cp01 = f2{cp.x, cp.y}, cp23 = f2{cp.z, cp.w};
            const f2 cq01 = f2{cq.x, cq.y}, cq23 = f2{cq.z, cq.w};
#pragma unroll
            for (int ii = 0; ii < IPW; ++ii) {
                const float4 w = W3v4[(u0 + ii) * NCH + kc];
                const f2 w01 = f2{w.x, w.y}, w23 = f2{w.z, w.w};
                pkfma_s(az[ii],  w01, cv01);  pkfma_s(az[ii],  w23, cv23);
                pkfma_s(ap2[ii], w01, cp01);  pkfma_s(ap2[ii], w23, cp23);
                pkfma_s(aq2[ii], w01, cq01);  pkfma_s(aq2[ii], w23, cq23);
            }
        }

        float pd1 = 0.f, pd2 = 0.f;
#pragma unroll
        for (int ii = 0; ii < IPW; ++ii) {
            const float z3 = az[ii].x + az[ii].y;
            const float zp = ap2[ii].x + ap2[ii].y;
            const float zq = aq2[ii].x + aq2[ii].y;
            float a, d1, d2; swish3(z3, a, d1, d2);
            const float w4 = W4[u0 + ii];
            pd1 = fmaf(w4, d1 * zp, pd1);
            pd2 = fmaf(w4, fmaf(d2 * zp, zp, d1 * zq), pd2);
        }
        pdS[wid][lane] = make_float2(pd1, pd2);
        __syncthreads();                         // b3: partials visible; all
                                                 // buf1 reads complete

        float g1 = 0.f, g2 = 0.f;
#pragma unroll
        for (int w = 0; w < WAVES; ++w) {
            const float2 p = pdS[w][lane];
            g1 += p.x; g2 += p.y;
        }
        // g = E'(y0) + E''(y0)*(y - y0) = E' - e*E''
        const float g = fmaf(g2, -e, g1);

        // Adam (replicated identically in all waves)
        m = fmaf(B1C, m, (1.f - B1C) * g);
        v = fmaf(B2C, v, (1.f - B2C) * g * g);
        const float mh = m / (1.f - pb1);
        const float vh = v / (1.f - pb2);
        y -= LR * mh / (sqrtf(vh) + AEPS);
        // pdS WAR: next write is 2 barriers away; buf0 WAR: its readers
        // finished before b2 of this step. Safe.
    }

    if (wid == 0) out[s] = y;
}

} // namespace

extern "C" void kernel_launch(void* const* d_in, const int* in_sizes, int n_in,
                              void* d_out, int out_size, void* d_ws, size_t ws_size,
                              hipStream_t stream) {
    const float* x   = (const float*)d_in[0];
    const float* eps = (const float*)d_in[1];
    const float* W1  = (const float*)d_in[2];
    const float* b1  = (const float*)d_in[3];
    const float* W2  = (const float*)d_in[4];
    const float* b2  = (const float*)d_in[5];
    const float* W3  = (const float*)d_in[6];
    const float* b3  = (const float*)d_in[7];
    const float* W4  = (const float*)d_in[8];
    float* out = (float*)d_out;

    ebm_kernel<<<BATCH / 64, 64 * WAVES, 0, stream>>>(x, eps, W1, b1, W2, b2, W3, b3, W4, out);
}

// Round 10
// 364.562 us; speedup vs baseline: 1.3661x; 1.3661x over previous
//
#include <hip/hip_runtime.h>

namespace {

typedef float f2 __attribute__((ext_vector_type(2)));

constexpr int BATCH = 32768;
constexpr int STEPS = 20;
constexpr int WD    = 48;
constexpr int WAVES = 6;           // waves per block
constexpr int IPW   = 8;           // units per wave (WAVES*IPW == WD)
constexpr int NCH   = WD / 4;      // 12 k-chunks of 4
constexpr float LR   = 0.1f;
constexpr float B1C  = 0.9f;
constexpr float B2C  = 0.999f;
constexpr float AEPS = 1e-8f;

__device__ __forceinline__ void swish3(float z, float& a, float& d1, float& d2) {
    const float sg = 1.f / (1.f + __expf(-z));
    const float sp = sg * (1.f - sg);
    d1 = fmaf(z, sp, sg);                      // swish'
    d2 = sp * fmaf(z, 1.f - 2.f * sg, 2.f);    // swish''
    a  = z * sg;
}

// Forced packed FMA: acc(pair) += w(SGPR pair) * a(pair). VOP3P allows one
// scalar source, so s_load'ed weights feed directly with no v_mov.
__device__ __forceinline__ void pkfma_s(f2& acc, f2 w, f2 a) {
    asm("v_pk_fma_f32 %0, %1, %2, %0" : "+v"(acc) : "s"(w), "v"(a));
}

// Sample-per-lane; 6 waves x 8 units. SINGLE chunk-major act buffer
// [NCH][64][4] per channel (conflict-free b128), 4 barriers/step, 40KB LDS
// -> 2 blocks/CU guaranteed (R9's 75KB ping-pong dropped to 1 block/CU).
// Weights uniform -> s_load scalar pipe; inner loop forced v_pk_fma_f32.
__global__ __launch_bounds__(384, 3) void ebm_kernel(
    const float* __restrict__ x_in,  const float* __restrict__ eps_in,
    const float* __restrict__ W1,    const float* __restrict__ b1,
    const float* __restrict__ W2,    const float* __restrict__ b2,
    const float* __restrict__ W3,    const float* __restrict__ b3,
    const float* __restrict__ W4,
    float* __restrict__ out)
{
    const int lane = threadIdx.x & 63;
    const int wid  = __builtin_amdgcn_readfirstlane(threadIdx.x >> 6);
    const int s    = blockIdx.x * 64 + lane;
    const int u0   = wid * IPW;                 // first unit owned by this wave
    const int c0   = wid * (IPW / 4);           // first chunk owned (2 chunks)

    __shared__ float aV[NCH][64][4];            // value channel, chunk-major
    __shared__ float aP[NCH][64][4];            // d/dy
    __shared__ float aQ[NCH][64][4];            // d2/dy2
    __shared__ float2 pdS[WAVES][64];           // per-wave (E', E'') partials

    const float4* __restrict__ W2v4 = reinterpret_cast<const float4*>(W2);
    const float4* __restrict__ W3v4 = reinterpret_cast<const float4*>(W3);

    const float xv = x_in[s];
    float y = 0.f, m = 0.f, v = 0.f;
    float pb1 = 1.f, pb2 = 1.f;

    for (int t = 0; t < STEPS; ++t) {
        const float e  = eps_in[t * BATCH + s];
        const float y0 = y + e;
        pb1 *= B1C; pb2 *= B2C;

        // ---- layer 1 (2 -> 48): this wave's 8 units ----
        float oa[IPW], op[IPW], oq[IPW];
#pragma unroll
        for (int ii = 0; ii < IPW; ++ii) {
            const int i = u0 + ii;
            const float w1x = W1[2 * i];
            const float w1y = W1[2 * i + 1];
            const float z1 = fmaf(w1y, y0, fmaf(w1x, xv, b1[i]));
            float a, d1, d2; swish3(z1, a, d1, d2);
            oa[ii] = a; op[ii] = d1 * w1y; oq[ii] = d2 * w1y * w1y;
        }
#pragma unroll
        for (int c = 0; c < IPW / 4; ++c) {
            *reinterpret_cast<float4*>(aV[c0 + c][lane]) = make_float4(oa[4*c], oa[4*c+1], oa[4*c+2], oa[4*c+3]);
            *reinterpret_cast<float4*>(aP[c0 + c][lane]) = make_float4(op[4*c], op[4*c+1], op[4*c+2], op[4*c+3]);
            *reinterpret_cast<float4*>(aQ[c0 + c][lane]) = make_float4(oq[4*c], oq[4*c+1], oq[4*c+2], oq[4*c+3]);
        }
        __syncthreads();                         // b1: L1 acts visible

        // ---- layer 2 (48 -> 48): packed FMA, scalar weights ----
        f2 az[IPW], ap2[IPW], aq2[IPW];
#pragma unroll
        for (int ii = 0; ii < IPW; ++ii) {
            az[ii]  = f2{b2[u0 + ii], 0.f};
            ap2[ii] = f2{0.f, 0.f};
            aq2[ii] = f2{0.f, 0.f};
        }
#pragma unroll 2
        for (int kc = 0; kc < NCH; ++kc) {
            const float4 cv = *reinterpret_cast<const float4*>(aV[kc][lane]);
            const float4 cp = *reinterpret_cast<const float4*>(aP[kc][lane]);
            const float4 cq = *reinterpret_cast<const float4*>(aQ[kc][lane]);
            const f2 cv01 = f2{cv.x, cv.y}, cv23 = f2{cv.z, cv.w};
            const f2 cp01 = f2{cp.x, cp.y}, cp23 = f2{cp.z, cp.w};
            const f2 cq01 = f2{cq.x, cq.y}, cq23 = f2{cq.z, cq.w};
#pragma unroll
            for (int ii = 0; ii < IPW; ++ii) {
                const float4 w = W2v4[(u0 + ii) * NCH + kc];   // uniform -> s_load_dwordx4
                const f2 w01 = f2{w.x, w.y}, w23 = f2{w.z, w.w};
                pkfma_s(az[ii],  w01, cv01);  pkfma_s(az[ii],  w23, cv23);
                pkfma_s(ap2[ii], w01, cp01);  pkfma_s(ap2[ii], w23, cp23);
                pkfma_s(aq2[ii], w01, cq01);  pkfma_s(aq2[ii], w23, cq23);
            }
        }
        __syncthreads();                         // b2: all act reads done (WAR)

#pragma unroll
        for (int ii = 0; ii < IPW; ++ii) {
            const float z2 = az[ii].x + az[ii].y;
            const float zp = ap2[ii].x + ap2[ii].y;
            const float zq = aq2[ii].x + aq2[ii].y;
            float a, d1, d2; swish3(z2, a, d1, d2);
            oa[ii] = a;
            op[ii] = d1 * zp;
            oq[ii] = fmaf(d2 * zp, zp, d1 * zq);
        }
#pragma unroll
        for (int c = 0; c < IPW / 4; ++c) {
            *reinterpret_cast<float4*>(aV[c0 + c][lane]) = make_float4(oa[4*c], oa[4*c+1], oa[4*c+2], oa[4*c+3]);
            *reinterpret_cast<float4*>(aP[c0 + c][lane]) = make_float4(op[4*c], op[4*c+1], op[4*c+2], op[4*c+3]);
            *reinterpret_cast<float4*>(aQ[c0 + c][lane]) = make_float4(oq[4*c], oq[4*c+1], oq[4*c+2], oq[4*c+3]);
        }
        __syncthreads();                         // b3: L2 acts visible

        // ---- layer 3 (48 -> 48) + W4 dot ----
#pragma unroll
        for (int ii = 0; ii < IPW; ++ii) {
            az[ii]  = f2{b3[u0 + ii], 0.f};
            ap2[ii] = f2{0.f, 0.f};
            aq2[ii] = f2{0.f, 0.f};
        }
#pragma unroll 2
        for (int kc = 0; kc < NCH; ++kc) {
            const float4 cv = *reinterpret_cast<const float4*>(aV[kc][lane]);
            const float4 cp = *reinterpret_cast<const float4*>(aP[kc][lane]);
            const float4 cq = *reinterpret_cast<const float4*>(aQ[kc][lane]);
            const f2 cv01 = f2{cv.x, cv.y}, cv23 = f2{cv.z, cv.w};
            const f2 cp01 = f2{cp.x, cp.y}, cp23 = f2{cp.z, cp.w};
            const f2 cq01 = f2{cq.x, cq.y}, cq23 = f2{cq.z, cq.w};
#pragma unroll
            for (int ii = 0; ii < IPW; ++ii) {
                const float4 w = W3v4[(u0 + ii) * NCH + kc];
                const f2 w01 = f2{w.x, w.y}, w23 = f2{w.z, w.w};
                pkfma_s(az[ii],  w01, cv01);  pkfma_s(az[ii],  w23, cv23);
                pkfma_s(ap2[ii], w01, cp01);  pkfma_s(ap2[ii], w23, cp23);
                pkfma_s(aq2[ii], w01, cq01);  pkfma_s(aq2[ii], w23, cq23);
            }
        }

        float pd1 = 0.f, pd2 = 0.f;
#pragma unroll
        for (int ii = 0; ii < IPW; ++ii) {
            const float z3 = az[ii].x + az[ii].y;
            const float zp = ap2[ii].x + ap2[ii].y;
            const float zq = aq2[ii].x + aq2[ii].y;
            float a, d1, d2; swish3(z3, a, d1, d2);
            const float w4 = W4[u0 + ii];
            pd1 = fmaf(w4, d1 * zp, pd1);
            pd2 = fmaf(w4, fmaf(d2 * zp, zp, d1 * zq), pd2);
        }
        pdS[wid][lane] = make_float2(pd1, pd2);
        __syncthreads();                         // b4: partials visible; guards
                                                 // act WAR for next step's L1

        float g1 = 0.f, g2 = 0.f;
#pragma unroll
        for (int w = 0; w < WAVES; ++w) {
            const float2 p = pdS[w][lane];
            g1 += p.x; g2 += p.y;
        }
        // g = E'(y0) + E''(y0)*(y - y0) = E' - e*E''
        const float g = fmaf(g2, -e, g1);

        // Adam (replicated identically in all waves)
        m = fmaf(B1C, m, (1.f - B1C) * g);
        v = fmaf(B2C, v, (1.f - B2C) * g * g);
        const float mh = m / (1.f - pb1);
        const float vh = v / (1.f - pb2);
        y -= LR * mh / (sqrtf(vh) + AEPS);
        // pdS WAR: next write is 3 barriers away -> safe.
    }

    if (wid == 0) out[s] = y;
}

} // namespace

extern "C" void kernel_launch(void* const* d_in, const int* in_sizes, int n_in,
                              void* d_out, int out_size, void* d_ws, size_t ws_size,
                              hipStream_t stream) {
    const float* x   = (const float*)d_in[0];
    const float* eps = (const float*)d_in[1];
    const float* W1  = (const float*)d_in[2];
    const float* b1  = (const float*)d_in[3];
    const float* W2  = (const float*)d_in[4];
    const float* b2  = (const float*)d_in[5];
    const float* W3  = (const float*)d_in[6];
    const float* b3  = (const float*)d_in[7];
    const float* W4  = (const float*)d_in[8];
    float* out = (float*)d_out;

    ebm_kernel<<<BATCH / 64, 64 * WAVES, 0, stream>>>(x, eps, W1, b1, W2, b2, W3, b3, W4, out);
}

// Round 11
// 183.063 us; speedup vs baseline: 2.7205x; 1.9915x over previous
//
#include <hip/hip_runtime.h>

namespace {

typedef _Float16 half8  __attribute__((ext_vector_type(8)));
typedef _Float16 half2v __attribute__((ext_vector_type(2)));
typedef float    f32x4  __attribute__((ext_vector_type(4)));

constexpr int BATCH = 32768;
constexpr int STEPS = 20;
constexpr int WD    = 48;
constexpr int AK    = 80;          // A row stride in f16 (160B, 16B-aligned, bank-friendly)
constexpr float LR   = 0.1f;
constexpr float B1C  = 0.9f;
constexpr float B2C  = 0.999f;
constexpr float AEPS = 1e-8f;

__device__ __forceinline__ void swish3(float z, float& a, float& d1, float& d2) {
    const float sg = 1.f / (1.f + __expf(-z));
    const float sp = sg * (1.f - sg);
    d1 = fmaf(z, sp, sg);                      // swish'
    d2 = sp * fmaf(z, 1.f - 2.f * sg, 2.f);    // swish''
    a  = z * sg;
}

// MFMA version. Block = 64 samples, 4 waves; wave w owns samples [16w,16w+16).
// Layers 2/3 are f16 MFMA GEMMs (3 Taylor channels share B=W); everything
// else (layer1, swish, derivative dot, Adam) is exact fp32.
// A-frag (16x16x32 f16): lane(c=l&15,g=l>>4) holds A[row=c][k=8g+j], j=0..7.
// B-frag: lane holds B[k=8g+j][col=c]  (B[k][i] = W[i][k] -> read W row-major).
// C/D: row=4g+reg, col=c (verified m89).
__global__ __launch_bounds__(256, 2) void ebm_kernel(
    const float* __restrict__ x_in,  const float* __restrict__ eps_in,
    const float* __restrict__ W1,    const float* __restrict__ b1,
    const float* __restrict__ W2,    const float* __restrict__ b2,
    const float* __restrict__ W3,    const float* __restrict__ b3,
    const float* __restrict__ W4,
    float* __restrict__ out)
{
    const int tid  = threadIdx.x;
    const int lane = tid & 63;
    const int wid  = __builtin_amdgcn_readfirstlane(tid >> 6);
    const int c    = lane & 15;
    const int g    = lane >> 4;
    const int blk  = blockIdx.x;

    __shared__ _Float16 Ah[3][64][AK];   // activation channels (a, a', a''), f16
    __shared__ float    y0S[64];
    __shared__ float    xS[64];
    __shared__ float2   pdS[64];

    // ---- one-time setup ----
    // zero the k-pad [48,64) (read by kc=1 fragments)
    for (int idx = tid; idx < 3 * 64 * 16; idx += 256) {
        const int ch = idx >> 10;
        const int r  = (idx & 1023) >> 4;
        const int k  = 48 + (idx & 15);
        Ah[ch][r][k] = (_Float16)0.f;
    }
    if (tid < 64) xS[tid] = x_in[blk * 64 + tid];

    // B fragments (W2/W3) -> registers, once. bfr[layer][tn][kc]
    half8 bfr[2][3][2];
#pragma unroll
    for (int lay = 0; lay < 2; ++lay) {
        const float* __restrict__ Wsrc = lay ? W3 : W2;
#pragma unroll
        for (int tn = 0; tn < 3; ++tn) {
#pragma unroll
            for (int kc = 0; kc < 2; ++kc) {
                const int i  = tn * 16 + c;
                const int k0 = kc * 32 + g * 8;
                half8 h;
                if (k0 >= WD) {
#pragma unroll
                    for (int j = 0; j < 8; ++j) h[j] = (_Float16)0.f;
                } else {
                    const float* src = Wsrc + i * WD + k0;
#pragma unroll
                    for (int j = 0; j < 8; ++j) h[j] = (_Float16)src[j];
                }
                bfr[lay][tn][kc] = h;
            }
        }
    }

    // layer-1 weights for this lane's 12 units [12g, 12g+12)
    float w1xr[12], w1yr[12], b1r[12];
#pragma unroll
    for (int j = 0; j < 12; ++j) {
        const int u = 12 * g + j;
        w1xr[j] = W1[2 * u];
        w1yr[j] = W1[2 * u + 1];
        b1r[j]  = b1[u];
    }
    // epilogue constants for this lane's 3 columns (i = 16tn + c)
    float w4r[3], b2r[3], b3r[3];
#pragma unroll
    for (int tn = 0; tn < 3; ++tn) {
        const int i = tn * 16 + c;
        w4r[tn] = W4[i]; b2r[tn] = b2[i]; b3r[tn] = b3[i];
    }

    __syncthreads();                       // setup visible

    float y = 0.f, m = 0.f, v = 0.f;
    float pb1 = 1.f, pb2 = 1.f, e = 0.f;
    const int sp = 16 * wid + c;           // sample this lane serves in L1/frag reads

    for (int t = 0; t < STEPS; ++t) {
        if (wid == 0) {
            e = eps_in[t * BATCH + blk * 64 + lane];
            y0S[lane] = y + e;
        }
        __syncthreads();                   // bar A: y0S visible

        // ---- layer 1 (2 -> 48), fp32, write f16 pairs ----
        {
            const float xv = xS[sp];
            const float yv = y0S[sp];
#pragma unroll
            for (int jp = 0; jp < 6; ++jp) {
                float a0, d10, d20, a1, d11, d21;
                const float z0 = fmaf(w1yr[2*jp],   yv, fmaf(w1xr[2*jp],   xv, b1r[2*jp]));
                const float z1 = fmaf(w1yr[2*jp+1], yv, fmaf(w1xr[2*jp+1], xv, b1r[2*jp+1]));
                swish3(z0, a0, d10, d20);
                swish3(z1, a1, d11, d21);
                const int u = 12 * g + 2 * jp;
                half2v pa, pp, pq;
                pa[0] = (_Float16)a0;                 pa[1] = (_Float16)a1;
                pp[0] = (_Float16)(d10 * w1yr[2*jp]); pp[1] = (_Float16)(d11 * w1yr[2*jp+1]);
                pq[0] = (_Float16)(d20 * w1yr[2*jp] * w1yr[2*jp]);
                pq[1] = (_Float16)(d21 * w1yr[2*jp+1] * w1yr[2*jp+1]);
                *reinterpret_cast<half2v*>(&Ah[0][sp][u]) = pa;
                *reinterpret_cast<half2v*>(&Ah[1][sp][u]) = pp;
                *reinterpret_cast<half2v*>(&Ah[2][sp][u]) = pq;
            }
        }
        __syncthreads();                   // bar B: L1 acts visible

        // ---- layer 2: A-frag reads, MFMA, swish epilogue ----
        half8 af[3][2];
#pragma unroll
        for (int ch = 0; ch < 3; ++ch)
#pragma unroll
            for (int kc = 0; kc < 2; ++kc)
                af[ch][kc] = *reinterpret_cast<const half8*>(&Ah[ch][sp][kc * 32 + g * 8]);
        __syncthreads();                   // bar C: all reads done before writes

        f32x4 acc[3][3];
#pragma unroll
        for (int ch = 0; ch < 3; ++ch)
#pragma unroll
            for (int tn = 0; tn < 3; ++tn) {
                acc[ch][tn] = f32x4{0.f, 0.f, 0.f, 0.f};
#pragma unroll
                for (int kc = 0; kc < 2; ++kc)
                    acc[ch][tn] = __builtin_amdgcn_mfma_f32_16x16x32_f16(
                        af[ch][kc], bfr[0][tn][kc], acc[ch][tn], 0, 0, 0);
            }

#pragma unroll
        for (int tn = 0; tn < 3; ++tn) {
#pragma unroll
            for (int r = 0; r < 4; ++r) {
                const float z  = acc[0][tn][r] + b2r[tn];
                const float zp = acc[1][tn][r];
                const float zq = acc[2][tn][r];
                float a, d1, d2; swish3(z, a, d1, d2);
                const int srow = 16 * wid + 4 * g + r;
                const int i    = 16 * tn + c;
                Ah[0][srow][i] = (_Float16)a;
                Ah[1][srow][i] = (_Float16)(d1 * zp);
                Ah[2][srow][i] = (_Float16)fmaf(d2 * zp, zp, d1 * zq);
            }
        }
        __syncthreads();                   // bar D: L2 acts visible

        // ---- layer 3: MFMA + derivative epilogue + reduce ----
#pragma unroll
        for (int ch = 0; ch < 3; ++ch)
#pragma unroll
            for (int kc = 0; kc < 2; ++kc)
                af[ch][kc] = *reinterpret_cast<const half8*>(&Ah[ch][sp][kc * 32 + g * 8]);

#pragma unroll
        for (int ch = 0; ch < 3; ++ch)
#pragma unroll
            for (int tn = 0; tn < 3; ++tn) {
                acc[ch][tn] = f32x4{0.f, 0.f, 0.f, 0.f};
#pragma unroll
                for (int kc = 0; kc < 2; ++kc)
                    acc[ch][tn] = __builtin_amdgcn_mfma_f32_16x16x32_f16(
                        af[ch][kc], bfr[1][tn][kc], acc[ch][tn], 0, 0, 0);
            }

        float pd1[4] = {0.f, 0.f, 0.f, 0.f};
        float pd2[4] = {0.f, 0.f, 0.f, 0.f};
#pragma unroll
        for (int tn = 0; tn < 3; ++tn) {
#pragma unroll
            for (int r = 0; r < 4; ++r) {
                const float z  = acc[0][tn][r] + b3r[tn];
                const float zp = acc[1][tn][r];
                const float zq = acc[2][tn][r];
                float a, d1, d2; swish3(z, a, d1, d2);
                pd1[r] = fmaf(w4r[tn], d1 * zp, pd1[r]);
                pd2[r] = fmaf(w4r[tn], fmaf(d2 * zp, zp, d1 * zq), pd2[r]);
            }
        }
#pragma unroll
        for (int off = 1; off < 16; off <<= 1) {
#pragma unroll
            for (int r = 0; r < 4; ++r) {
                pd1[r] += __shfl_xor(pd1[r], off);
                pd2[r] += __shfl_xor(pd2[r], off);
            }
        }
        if (c < 4) {   // lane c writes reg=c's pair for sample 16w + 4g + c
            const float a1 = (c == 0) ? pd1[0] : (c == 1) ? pd1[1] : (c == 2) ? pd1[2] : pd1[3];
            const float a2 = (c == 0) ? pd2[0] : (c == 1) ? pd2[1] : (c == 2) ? pd2[2] : pd2[3];
            pdS[16 * wid + 4 * g + c] = make_float2(a1, a2);
        }
        __syncthreads();                   // bar E: pdS visible

        // ---- Adam (wave 0 only; lane = sample) ----
        if (wid == 0) {
            const float2 pd = pdS[lane];
            const float gg = fmaf(pd.y, -e, pd.x);    // E' - e*E''
            pb1 *= B1C; pb2 *= B2C;
            m = fmaf(B1C, m, (1.f - B1C) * gg);
            v = fmaf(B2C, v, (1.f - B2C) * gg * gg);
            const float mh = m / (1.f - pb1);
            const float vh = v / (1.f - pb2);
            y -= LR * mh / (sqrtf(vh) + AEPS);
        }
        // next-iter y0S write happens after bar E -> WAR-safe vs this step's reads
    }

    if (wid == 0) out[blk * 64 + lane] = y;
}

} // namespace

extern "C" void kernel_launch(void* const* d_in, const int* in_sizes, int n_in,
                              void* d_out, int out_size, void* d_ws, size_t ws_size,
                              hipStream_t stream) {
    const float* x   = (const float*)d_in[0];
    const float* eps = (const float*)d_in[1];
    const float* W1  = (const float*)d_in[2];
    const float* b1  = (const float*)d_in[3];
    const float* W2  = (const float*)d_in[4];
    const float* b2  = (const float*)d_in[5];
    const float* W3  = (const float*)d_in[6];
    const float* b3  = (const float*)d_in[7];
    const float* W4  = (const float*)d_in[8];
    float* out = (float*)d_out;

    ebm_kernel<<<BATCH / 64, 256, 0, stream>>>(x, eps, W1, b1, W2, b2, W3, b3, W4, out);
}

// Round 12
// 179.059 us; speedup vs baseline: 2.7814x; 1.0224x over previous
//
#include <hip/hip_runtime.h>

namespace {

typedef _Float16 half8 __attribute__((ext_vector_type(8)));
typedef float    f32x4 __attribute__((ext_vector_type(4)));

constexpr int BATCH = 32768;
constexpr int STEPS = 20;
constexpr int WD    = 48;
constexpr int SPW   = 16;          // samples per wave (one MFMA M-tile)
constexpr int AKW   = 72;          // Ah row stride in f16 (144B: 16B-aligned, spreads bank quads)
constexpr float LR   = 0.1f;
constexpr float B1C  = 0.9f;
constexpr float B2C  = 0.999f;
constexpr float AEPS = 1e-8f;

__device__ __forceinline__ void swish3(float z, float& a, float& d1, float& d2) {
    const float sg = 1.f / (1.f + __expf(-z));
    const float sp = sg * (1.f - sg);
    d1 = fmaf(z, sp, sg);                      // swish'
    d2 = sp * fmaf(z, 1.f - 2.f * sg, 2.f);    // swish''
    a  = z * sg;
}

// Wave-autonomous MFMA kernel: 1 wave = 16 samples, ZERO __syncthreads.
// Lane (c = lane&15, g = lane>>4).
// A-frag (16x16x32 f16): lane holds A[row=c][k = kc*32 + 8g + j].
// B-frag: lane holds B[k][col=c] = W[col][k].  C/D: row = 4g+reg, col = c.
// Layer-1 writes A-fragments DIRECTLY in registers (its units == its k-slots).
// Only the L2->L3 boundary transposes through wave-private LDS (DS ops are
// in-order within a wave; compiler fence + lgkmcnt, no barrier).
__global__ __launch_bounds__(64, 2) void ebm_kernel(
    const float* __restrict__ x_in,  const float* __restrict__ eps_in,
    const float* __restrict__ W1,    const float* __restrict__ b1,
    const float* __restrict__ W2,    const float* __restrict__ b2,
    const float* __restrict__ W3,    const float* __restrict__ b3,
    const float* __restrict__ W4,
    float* __restrict__ out)
{
    const int lane = threadIdx.x & 63;
    const int c    = lane & 15;
    const int g    = lane >> 4;
    const int s0   = blockIdx.x * SPW;
    const int sc   = s0 + c;               // this lane's sample
    const bool hiv = (g < 2);              // kc=1 k-slots are real units (k<48)

    __shared__ __attribute__((aligned(16))) _Float16 Ah[3][SPW][AKW];
    __shared__ float2 pdS[SPW];

    // ---- one-time setup (all in registers) ----
    // Layer-1 weights for this lane's 16 k-slots (zeros for pad slots:
    // z=0 -> a=0, a'=d1*0=0, a''=0, so pad contributes exactly 0).
    float w1x[16], w1y[16], b1r[16];
#pragma unroll
    for (int j = 0; j < 8; ++j) {
        const int u = 8 * g + j;
        w1x[j] = W1[2 * u]; w1y[j] = W1[2 * u + 1]; b1r[j] = b1[u];
    }
#pragma unroll
    for (int j = 0; j < 8; ++j) {
        const int u = 32 + 8 * g + j;      // valid only when g<2
        w1x[8 + j] = hiv ? W1[2 * u]     : 0.f;
        w1y[8 + j] = hiv ? W1[2 * u + 1] : 0.f;
        b1r[8 + j] = hiv ? b1[u]         : 0.f;
    }

    // B fragments (W2, W3) in registers, f16.
    half8 bfr[2][3][2];
#pragma unroll
    for (int lay = 0; lay < 2; ++lay) {
        const float* __restrict__ Wsrc = lay ? W3 : W2;
#pragma unroll
        for (int tn = 0; tn < 3; ++tn) {
#pragma unroll
            for (int kc = 0; kc < 2; ++kc) {
                const int i  = tn * 16 + c;
                const int k0 = kc * 32 + g * 8;
                half8 h;
#pragma unroll
                for (int j = 0; j < 8; ++j) h[j] = (_Float16)0.f;
                if (k0 < WD) {
                    const float* src = Wsrc + i * WD + k0;
#pragma unroll
                    for (int j = 0; j < 8; ++j) h[j] = (_Float16)src[j];
                }
                bfr[lay][tn][kc] = h;
            }
        }
    }

    // Epilogue constants for this lane's 3 output columns (i = 16tn + c).
    float w4r[3], b2r[3], b3r[3];
#pragma unroll
    for (int tn = 0; tn < 3; ++tn) {
        const int i = tn * 16 + c;
        w4r[tn] = W4[i]; b2r[tn] = b2[i]; b3r[tn] = b3[i];
    }

    const float xv = x_in[sc];
    float y = 0.f, m = 0.f, v = 0.f;
    float pb1 = 1.f, pb2 = 1.f;

#pragma unroll 1
    for (int t = 0; t < STEPS; ++t) {
        const float e  = eps_in[t * BATCH + sc];   // same value across g-copies
        const float y0 = y + e;
        pb1 *= B1C; pb2 *= B2C;

        // ---- layer 1 (2 -> 48): build A-fragments directly in registers ----
        half8 af[3][2];
#pragma unroll
        for (int kc = 0; kc < 2; ++kc) {
#pragma unroll
            for (int j = 0; j < 8; ++j) {
                const int sl = kc * 8 + j;
                const float z1 = fmaf(w1y[sl], y0, fmaf(w1x[sl], xv, b1r[sl]));
                float a, d1, d2; swish3(z1, a, d1, d2);
                af[0][kc][j] = (_Float16)a;
                af[1][kc][j] = (_Float16)(d1 * w1y[sl]);
                af[2][kc][j] = (_Float16)(d2 * w1y[sl] * w1y[sl]);
            }
        }

        // ---- layer 2 GEMM: 3 channels x 3 col-tiles x 2 k-chunks ----
        f32x4 acc[3][3];
#pragma unroll
        for (int ch = 0; ch < 3; ++ch)
#pragma unroll
            for (int tn = 0; tn < 3; ++tn) {
                acc[ch][tn] = f32x4{0.f, 0.f, 0.f, 0.f};
#pragma unroll
                for (int kc = 0; kc < 2; ++kc)
                    acc[ch][tn] = __builtin_amdgcn_mfma_f32_16x16x32_f16(
                        af[ch][kc], bfr[0][tn][kc], acc[ch][tn], 0, 0, 0);
            }

        // ---- layer-2 epilogue -> wave-private LDS transpose ----
        asm volatile("" ::: "memory");     // keep writes after prior-step reads
#pragma unroll
        for (int tn = 0; tn < 3; ++tn) {
#pragma unroll
            for (int r = 0; r < 4; ++r) {
                const float z  = acc[0][tn][r] + b2r[tn];
                const float zp = acc[1][tn][r];
                const float zq = acc[2][tn][r];
                float a, d1, d2; swish3(z, a, d1, d2);
                const int row = 4 * g + r;         // sample within tile
                const int col = 16 * tn + c;       // unit
                Ah[0][row][col] = (_Float16)a;
                Ah[1][row][col] = (_Float16)(d1 * zp);
                Ah[2][row][col] = (_Float16)fmaf(d2 * zp, zp, d1 * zq);
            }
        }
        asm volatile("s_waitcnt lgkmcnt(0)" ::: "memory");
        __builtin_amdgcn_sched_barrier(0);

        // ---- read layer-3 A-fragments (row = c) ----
#pragma unroll
        for (int ch = 0; ch < 3; ++ch) {
            af[ch][0] = *reinterpret_cast<const half8*>(&Ah[ch][c][8 * g]);
            half8 z8;
#pragma unroll
            for (int j = 0; j < 8; ++j) z8[j] = (_Float16)0.f;
            if (hiv) z8 = *reinterpret_cast<const half8*>(&Ah[ch][c][32 + 8 * g]);
            af[ch][1] = z8;                // pad cols never read -> no NaN risk
        }

        // ---- layer 3 GEMM ----
#pragma unroll
        for (int ch = 0; ch < 3; ++ch)
#pragma unroll
            for (int tn = 0; tn < 3; ++tn) {
                acc[ch][tn] = f32x4{0.f, 0.f, 0.f, 0.f};
#pragma unroll
                for (int kc = 0; kc < 2; ++kc)
                    acc[ch][tn] = __builtin_amdgcn_mfma_f32_16x16x32_f16(
                        af[ch][kc], bfr[1][tn][kc], acc[ch][tn], 0, 0, 0);
            }

        // ---- layer-3 derivative epilogue + reduction over units ----
        float pd1[4] = {0.f, 0.f, 0.f, 0.f};
        float pd2[4] = {0.f, 0.f, 0.f, 0.f};
#pragma unroll
        for (int tn = 0; tn < 3; ++tn) {
#pragma unroll
            for (int r = 0; r < 4; ++r) {
                const float z  = acc[0][tn][r] + b3r[tn];
                const float zp = acc[1][tn][r];
                const float zq = acc[2][tn][r];
                float a, d1, d2; swish3(z, a, d1, d2);
                pd1[r] = fmaf(w4r[tn], d1 * zp, pd1[r]);
                pd2[r] = fmaf(w4r[tn], fmaf(d2 * zp, zp, d1 * zq), pd2[r]);
            }
        }
#pragma unroll
        for (int off = 1; off < 16; off <<= 1) {
#pragma unroll
            for (int r = 0; r < 4; ++r) {
                pd1[r] += __shfl_xor(pd1[r], off);
                pd2[r] += __shfl_xor(pd2[r], off);
            }
        }
        asm volatile("" ::: "memory");
        if (c < 4) {                        // sample q = 4g + c  (static select)
            const float a1 = (c == 0) ? pd1[0] : (c == 1) ? pd1[1] : (c == 2) ? pd1[2] : pd1[3];
            const float a2 = (c == 0) ? pd2[0] : (c == 1) ? pd2[1] : (c == 2) ? pd2[2] : pd2[3];
            pdS[4 * g + c] = make_float2(a1, a2);
        }
        asm volatile("s_waitcnt lgkmcnt(0)" ::: "memory");
        __builtin_amdgcn_sched_barrier(0);
        const float2 pd = pdS[c];

        // ---- Adam (replicated across the 4 g-copies of each sample) ----
        const float gg = fmaf(pd.y, -e, pd.x);     // E'(y0) - e*E''(y0)
        m = fmaf(B1C, m, (1.f - B1C) * gg);
        v = fmaf(B2C, v, (1.f - B2C) * gg * gg);
        const float mh = m / (1.f - pb1);
        const float vh = v / (1.f - pb2);
        y -= LR * mh / (sqrtf(vh) + AEPS);
    }

    if (g == 0) out[sc] = y;
}

} // namespace

extern "C" void kernel_launch(void* const* d_in, const int* in_sizes, int n_in,
                              void* d_out, int out_size, void* d_ws, size_t ws_size,
                              hipStream_t stream) {
    const float* x   = (const float*)d_in[0];
    const float* eps = (const float*)d_in[1];
    const float* W1  = (const float*)d_in[2];
    const float* b1  = (const float*)d_in[3];
    const float* W2  = (const float*)d_in[4];
    const float* b2  = (const float*)d_in[5];
    const float* W3  = (const float*)d_in[6];
    const float* b3  = (const float*)d_in[7];
    const float* W4  = (const float*)d_in[8];
    float* out = (float*)d_out;

    ebm_kernel<<<BATCH / SPW, 64, 0, stream>>>(x, eps, W1, b1, W2, b2, W3, b3, W4, out);
}

// Round 13
// 148.821 us; speedup vs baseline: 3.3465x; 1.2032x over previous
//
#include <hip/hip_runtime.h>

namespace {

typedef _Float16 half8  __attribute__((ext_vector_type(8)));
typedef _Float16 half2v __attribute__((ext_vector_type(2)));
typedef float    f32x4  __attribute__((ext_vector_type(4)));
typedef unsigned int uint4v __attribute__((ext_vector_type(4)));

constexpr int BATCH = 32768;
constexpr int STEPS = 20;
constexpr int WD    = 48;
constexpr int SPW   = 16;          // samples per wave (one MFMA M-tile)
constexpr int AKW   = 72;          // Ah row stride in f16 (144B)
constexpr float LR   = 0.1f;
constexpr float B1C  = 0.9f;
constexpr float B2C  = 0.999f;
constexpr float AEPS = 1e-8f;

__device__ __forceinline__ void swish3(float z, float& a, float& d1, float& d2) {
    const float sg = __builtin_amdgcn_rcpf(1.f + __expf(-z));   // fast sigmoid
    const float sp = sg * (1.f - sg);
    d1 = fmaf(z, sp, sg);                      // swish'
    d2 = sp * fmaf(z, 1.f - 2.f * sg, 2.f);    // swish''
    a  = z * sg;
}

// Wave-autonomous MFMA kernel: 1 wave = 16 samples, zero __syncthreads.
// Lane (c = lane&15, g = lane>>4).
// Unit permutation: k-slot (kc,g,j) -> unit = 12g + 8kc + j  (kc=1,j>=4 = pad).
// Every lane computes exactly 12 real L1 slots; pad slots are uniform zeros.
// A-frag: lane holds A[row=c][k=kc*32+8g+j]. B-frag: B[k][col=c]=W[col][perm(k)].
// C/D: row=4g+reg, col=c. L2->L3 transpose through wave-private LDS
// (in-order DS + lgkmcnt, no barrier). pd exchange via ds_bpermute.
__global__ __launch_bounds__(64, 2) void ebm_kernel(
    const float* __restrict__ x_in,  const float* __restrict__ eps_in,
    const float* __restrict__ W1,    const float* __restrict__ b1,
    const float* __restrict__ W2,    const float* __restrict__ b2,
    const float* __restrict__ W3,    const float* __restrict__ b3,
    const float* __restrict__ W4,
    float* __restrict__ out)
{
    const int lane = threadIdx.x & 63;
    const int c    = lane & 15;
    const int g    = lane >> 4;
    const int sc   = blockIdx.x * SPW + c;     // this lane's sample

    __shared__ __attribute__((aligned(16))) _Float16 Ah[3][SPW][AKW];

    // ---- zero Ah once (pad k-slot columns must read as 0 in L3 frags) ----
    {
        unsigned int* p = reinterpret_cast<unsigned int*>(&Ah[0][0][0]);
        for (int i = lane; i < 3 * SPW * AKW / 2; i += 64) p[i] = 0u;
    }

    // ---- one-time setup ----
    // Layer-1 weights for this lane's 12 real units u = 12g + 0..11.
    float w1x[12], w1y[12], b1r[12];
#pragma unroll
    for (int j = 0; j < 12; ++j) {
        const int u = 12 * g + j;
        w1x[j] = W1[2 * u]; w1y[j] = W1[2 * u + 1]; b1r[j] = b1[u];
    }

    // B fragments (W2, W3) in registers, f16, permuted k-side.
    half8 bfr[2][3][2];
#pragma unroll
    for (int lay = 0; lay < 2; ++lay) {
        const float* __restrict__ Wsrc = lay ? W3 : W2;
#pragma unroll
        for (int tn = 0; tn < 3; ++tn) {
            const int col = 16 * tn + c;
#pragma unroll
            for (int j = 0; j < 8; ++j)
                bfr[lay][tn][0][j] = (_Float16)Wsrc[col * WD + 12 * g + j];
#pragma unroll
            for (int j = 0; j < 4; ++j)
                bfr[lay][tn][1][j] = (_Float16)Wsrc[col * WD + 12 * g + 8 + j];
#pragma unroll
            for (int j = 4; j < 8; ++j)
                bfr[lay][tn][1][j] = (_Float16)0.f;
        }
    }

    // Epilogue constants for this lane's 3 output columns (i = 16tn + c),
    // and the permuted Ah write column for unit i.
    float w4r[3], b2r[3], b3r[3];
    int colw[3];
#pragma unroll
    for (int tn = 0; tn < 3; ++tn) {
        const int u = 16 * tn + c;
        w4r[tn] = W4[u]; b2r[tn] = b2[u]; b3r[tn] = b3[u];
        const int gu  = u / 12;
        const int rem = u - 12 * gu;
        const int kcu = rem >> 3;
        colw[tn] = 32 * kcu + 8 * gu + (rem - 8 * kcu);
    }

    // Launder persistent operands so the compiler cannot sink/remat their
    // defining loads+converts into the step loop (R12: VGPR=84 => it did).
#pragma unroll
    for (int l = 0; l < 2; ++l)
#pragma unroll
        for (int tn = 0; tn < 3; ++tn)
#pragma unroll
            for (int kc = 0; kc < 2; ++kc)
                asm volatile("" : "+v"(bfr[l][tn][kc]));
#pragma unroll
    for (int j = 0; j < 12; ++j)
        asm volatile("" : "+v"(w1x[j]), "+v"(w1y[j]), "+v"(b1r[j]));
#pragma unroll
    for (int tn = 0; tn < 3; ++tn)
        asm volatile("" : "+v"(w4r[tn]), "+v"(b2r[tn]), "+v"(b3r[tn]));

    const float xv = x_in[sc];
    float y = 0.f, m = 0.f, v = 0.f;
    float pb1 = 1.f, pb2 = 1.f;
    float e = eps_in[sc];                      // step-0 eps (prefetched)

#pragma unroll 1
    for (int t = 0; t < STEPS; ++t) {
        const int tn1 = (t + 1 < STEPS) ? t + 1 : STEPS - 1;
        const float e_nxt = eps_in[tn1 * BATCH + sc];   // prefetch next step
        const float y0 = y + e;
        pb1 *= B1C; pb2 *= B2C;

        // ---- layer 1 (2 -> 48): 12 real slots -> A-fragments in registers ----
        uint4v afu[3][2];
#pragma unroll
        for (int jp = 0; jp < 6; ++jp) {       // slot pair (2jp, 2jp+1)
            const int s0 = 2 * jp, s1 = 2 * jp + 1;
            float a0, d10, d20, a1, d11, d21;
            const float z0 = fmaf(w1y[s0], y0, fmaf(w1x[s0], xv, b1r[s0]));
            const float z1 = fmaf(w1y[s1], y0, fmaf(w1x[s1], xv, b1r[s1]));
            swish3(z0, a0, d10, d20);
            swish3(z1, a1, d11, d21);
            const int kc = jp >> 2, wrd = jp & 3;
            afu[0][kc][wrd] = __builtin_bit_cast(unsigned int,
                __builtin_amdgcn_cvt_pkrtz(a0, a1));
            afu[1][kc][wrd] = __builtin_bit_cast(unsigned int,
                __builtin_amdgcn_cvt_pkrtz(d10 * w1y[s0], d11 * w1y[s1]));
            afu[2][kc][wrd] = __builtin_bit_cast(unsigned int,
                __builtin_amdgcn_cvt_pkrtz(d20 * w1y[s0] * w1y[s0],
                                           d21 * w1y[s1] * w1y[s1]));
        }
#pragma unroll
        for (int ch = 0; ch < 3; ++ch) { afu[ch][1][2] = 0u; afu[ch][1][3] = 0u; }

        half8 af[3][2];
#pragma unroll
        for (int ch = 0; ch < 3; ++ch)
#pragma unroll
            for (int kc = 0; kc < 2; ++kc)
                af[ch][kc] = __builtin_bit_cast(half8, afu[ch][kc]);

        // ---- layer 2 GEMM ----
        f32x4 acc[3][3];
#pragma unroll
        for (int ch = 0; ch < 3; ++ch)
#pragma unroll
            for (int tn = 0; tn < 3; ++tn) {
                acc[ch][tn] = f32x4{0.f, 0.f, 0.f, 0.f};
#pragma unroll
                for (int kc = 0; kc < 2; ++kc)
                    acc[ch][tn] = __builtin_amdgcn_mfma_f32_16x16x32_f16(
                        af[ch][kc], bfr[0][tn][kc], acc[ch][tn], 0, 0, 0);
            }

        // ---- layer-2 epilogue -> wave-private LDS transpose (perm cols) ----
        asm volatile("" ::: "memory");
#pragma unroll
        for (int tn = 0; tn < 3; ++tn) {
#pragma unroll
            for (int r = 0; r < 4; ++r) {
                const float z  = acc[0][tn][r] + b2r[tn];
                const float zp = acc[1][tn][r];
                const float zq = acc[2][tn][r];
                float a, d1, d2; swish3(z, a, d1, d2);
                const int row = 4 * g + r;
                Ah[0][row][colw[tn]] = (_Float16)a;
                Ah[1][row][colw[tn]] = (_Float16)(d1 * zp);
                Ah[2][row][colw[tn]] = (_Float16)fmaf(d2 * zp, zp, d1 * zq);
            }
        }
        asm volatile("s_waitcnt lgkmcnt(0)" ::: "memory");
        __builtin_amdgcn_sched_barrier(0);

        // ---- layer-3 A-fragments (pad columns are zeros) ----
#pragma unroll
        for (int ch = 0; ch < 3; ++ch) {
            af[ch][0] = *reinterpret_cast<const half8*>(&Ah[ch][c][8 * g]);
            af[ch][1] = *reinterpret_cast<const half8*>(&Ah[ch][c][32 + 8 * g]);
        }

        // ---- layer 3 GEMM ----
#pragma unroll
        for (int ch = 0; ch < 3; ++ch)
#pragma unroll
            for (int tn = 0; tn < 3; ++tn) {
                acc[ch][tn] = f32x4{0.f, 0.f, 0.f, 0.f};
#pragma unroll
                for (int kc = 0; kc < 2; ++kc)
                    acc[ch][tn] = __builtin_amdgcn_mfma_f32_16x16x32_f16(
                        af[ch][kc], bfr[1][tn][kc], acc[ch][tn], 0, 0, 0);
            }

        // ---- layer-3 derivative epilogue + reduce over units ----
        float pd1[4] = {0.f, 0.f, 0.f, 0.f};
        float pd2[4] = {0.f, 0.f, 0.f, 0.f};
#pragma unroll
        for (int tn = 0; tn < 3; ++tn) {
#pragma unroll
            for (int r = 0; r < 4; ++r) {
                const float z  = acc[0][tn][r] + b3r[tn];
                const float zp = acc[1][tn][r];
                const float zq = acc[2][tn][r];
                float a, d1, d2; swish3(z, a, d1, d2);
                pd1[r] = fmaf(w4r[tn], d1 * zp, pd1[r]);
                pd2[r] = fmaf(w4r[tn], fmaf(d2 * zp, zp, d1 * zq), pd2[r]);
            }
        }
#pragma unroll
        for (int off = 1; off < 16; off <<= 1) {
#pragma unroll
            for (int r = 0; r < 4; ++r) {
                pd1[r] += __shfl_xor(pd1[r], off);
                pd2[r] += __shfl_xor(pd2[r], off);
            }
        }
        // lane (c,g) needs sample c = 4*(c>>2)+(c&3): take reg (c&3) from
        // g-group (c>>2) via one bpermute per value.
        const int c3 = c & 3;
        const float s1 = (c3 == 0) ? pd1[0] : (c3 == 1) ? pd1[1] : (c3 == 2) ? pd1[2] : pd1[3];
        const float s2 = (c3 == 0) ? pd2[0] : (c3 == 1) ? pd2[1] : (c3 == 2) ? pd2[2] : pd2[3];
        const int src = ((c >> 2) << 4) | c;
        const float gd1 = __shfl(s1, src, 64);
        const float gd2 = __shfl(s2, src, 64);

        // ---- Adam (replicated across the 4 g-copies of each sample) ----
        const float gg = fmaf(gd2, -e, gd1);    // E'(y0) - e*E''(y0)
        m = fmaf(B1C, m, (1.f - B1C) * gg);
        v = fmaf(B2C, v, (1.f - B2C) * gg * gg);
        const float mh = m * __builtin_amdgcn_rcpf(1.f - pb1);
        const float vh = v * __builtin_amdgcn_rcpf(1.f - pb2);
        y -= LR * mh * __builtin_amdgcn_rcpf(__builtin_amdgcn_sqrtf(vh) + AEPS);
        e = e_nxt;
    }

    if (g == 0) out[sc] = y;
}

} // namespace

extern "C" void kernel_launch(void* const* d_in, const int* in_sizes, int n_in,
                              void* d_out, int out_size, void* d_ws, size_t ws_size,
                              hipStream_t stream) {
    const float* x   = (const float*)d_in[0];
    const float* eps = (const float*)d_in[1];
    const float* W1  = (const float*)d_in[2];
    const float* b1  = (const float*)d_in[3];
    const float* W2  = (const float*)d_in[4];
    const float* b2  = (const float*)d_in[5];
    const float* W3  = (const float*)d_in[6];
    const float* b3  = (const float*)d_in[7];
    const float* W4  = (const float*)d_in[8];
    float* out = (float*)d_out;

    ebm_kernel<<<BATCH / SPW, 64, 0, stream>>>(x, eps, W1, b1, W2, b2, W3, b3, W4, out);
}